// Round 18
// baseline (264.022 us; speedup 1.0000x reference)
//
#include <hip/hip_runtime.h>
#include <stdint.h>

#define THREADS 256
#define SPB 8                  // samples per block -> 32 A-rows
#define CHUNK_WORDS 2048       // one K=16 W chunk: dense f16-hi image (8 KB)
#define NCHUNK_TOT 64          // 4 layers x 16 chunks, linearized
#define PP 4096                // ping-pong plane stride in words (16 KB)

typedef _Float16 f16x8 __attribute__((ext_vector_type(8)));
typedef float f32x16 __attribute__((ext_vector_type(16)));

union FragH { uint32_t u[4]; f16x8 v; };

// Barrier that waits ONLY on LDS (lgkmcnt), not global loads: __syncthreads
// emits "s_waitcnt vmcnt(0) lgkmcnt(0); s_barrier", draining the in-flight
// B-ring prefetches at every layer boundary even though no cross-wave
// dependency flows through global memory here (all are LDS). Register
// consumers of qh[] are ordered by the compiler's per-register vmcnt
// tracking independently of barriers. Verified r17: 206.7->202.8 us.
#define BARRIER() asm volatile("s_waitcnt lgkmcnt(0)\n\ts_barrier" ::: "memory")

// ONE-OP packed f32x2 -> f16x2 (RTZ). Proven tolerable (absmax 3.66e-4).
__device__ __forceinline__ uint32_t pkrtz(float a, float b) {
    return __builtin_bit_cast(uint32_t, __builtin_amdgcn_cvt_pkrtz(a, b));
}
__device__ __forceinline__ float frcp(float x) {       // v_rcp_f32 (~1 ulp)
    return __builtin_amdgcn_rcpf(x);
}
__device__ __forceinline__ float wsum(float v) {
    #pragma unroll
    for (int off = 32; off > 0; off >>= 1) v += __shfl_xor(v, off, 64);
    return v;
}
// MFMA with B taken straight from the prefetch ring (no union round-trip)
__device__ __forceinline__ f32x16 mfma16(f16x8 a, uint4 b, f32x16 c) {
    return __builtin_amdgcn_mfma_f32_32x32x16_f16(a, __builtin_bit_cast(f16x8, b), c, 0, 0, 0);
}

// ---- pre-kernel: pack W into a DENSE f16-hi k-pair chunk image (512 KB) ----
// word idx = l*32768 + kt*2048 + s8*1024 + n*4 + w
// PAIR PERMUTATION: kp = kt*8+s8*4+w holds klo = 2*(kp&~31)+(kp&31), khi=klo+32
// -> a lane's two output columns (n, n+32) form one f16 k-pair IN-LANE.
__global__ __launch_bounds__(256) void pack_w(const float* __restrict__ w_hid,
                                              const float* __restrict__ w_out,
                                              uint32_t* __restrict__ Wp) {
    int t  = blockIdx.x * 256 + threadIdx.x;       // 0..32767
    int l  = t >> 13;
    int r  = t & 8191;
    int kt = r >> 9;
    int r2 = r & 511;
    int s8 = r2 >> 8;
    int n  = r2 & 255;
    const float* Wsrc = (l < 3) ? (w_hid + l * 65536) : w_out;
    uint32_t wd[4];
    #pragma unroll
    for (int w = 0; w < 4; ++w) {
        int kp  = kt * 8 + s8 * 4 + w;             // 0..127
        int klo = 2 * (kp & ~31) + (kp & 31);
        wd[w] = pkrtz(Wsrc[klo * 256 + n], Wsrc[(klo + 32) * 256 + n]);
    }
    *(uint4*)&Wp[l * 32768 + kt * 2048 + s8 * 1024 + n * 4] = *(uint4*)wd;
}

// Base = round-17 kernel (best verified: 202.8 us dispatch, no spill at
// (256,4)): sA 32 KB ping-pong (plane l&1 read, other written -> no
// pre-epilogue barrier), 4-deep qh[4][2] ring with uniform-base saddr,
// lgkmcnt-only barriers, register-lean two-half input layer, single-shot
// fp32 E overlay. Register demand ~124 -> 4 waves/SIMD is this structure's
// ceiling (r12-r16: every min_waves>=5 config spilled catastrophically).
//
// r18 deltas (micro-trims, evidence-backed):
//  1. s_setprio REMOVED: learn_hip m190 measured setprio negative (-1.5%)
//     on lockstep multi-wave GEMM blocks -- our within-block structure.
//  2. Dead tail refills skipped (l==3, tt>=12 loaded never-consumed data:
//     8 uint4 loads/thread, ~6% of B-load count). tt is compile-time ->
//     only uniform scc branches.
__global__ __launch_bounds__(THREADS, 4) void divfree_mfma(
    const float* __restrict__ x,
    const uint32_t* __restrict__ Wp,
    const float* __restrict__ w_in,
    const float* __restrict__ b_in,
    const float* __restrict__ b_hid,
    const float* __restrict__ b_out,
    float* __restrict__ out)
{
    __shared__ uint32_t lds[8192];                 // 32 KB = 2 ping-pong planes
    const int tid  = threadIdx.x;
    const int wave = tid >> 6, lane = tid & 63;
    const int l5 = lane >> 5, ln = lane & 31;
    const int s0 = blockIdx.x * SPB;
    const int cg = wave;                           // column group (64 cols)
    const int n1 = cg * 64 + ln;                   // lower output column
    const int voff = l5 * 1024 + n1 * 4;           // per-lane B word offset

    // 4-deep software-pipelined B prefetch (hi image), 2 col-tiles/slot.
    // These 8 loads stay in flight across the input layer AND its barrier.
    uint4 qh[4][2];
    #pragma unroll
    for (int c = 0; c < 4; ++c) {
        const uint32_t* Bc = Wp + c * CHUNK_WORDS; // uniform base -> saddr
        qh[c][0] = *(const uint4*)(Bc + voff);
        qh[c][1] = *(const uint4*)(Bc + voff + 128);
    }

    { // ---- input layer, register-lean two-half form ----
      // thread owns (kq = tid&31, sample s = tid>>5); covers 4 state rows.
      // A-half computed fully first; only vA[16] carries into the B-half.
        const int kq = tid & 31;                   // 0..31
        const int s  = tid >> 5;                   // 0..7
        const int kA = ((kq >> 3) << 6) + ((kq & 7) << 2);
        const float x0 = x[(s0 + s) * 3 + 0];
        const float x1 = x[(s0 + s) * 3 + 1];
        const float x2 = x[(s0 + s) * 3 + 2];
        float vA[16];                              // [r*4+e]
        {
            float4 w0 = *(const float4*)&w_in[kA];
            float4 w1 = *(const float4*)&w_in[256 + kA];
            float4 w2 = *(const float4*)&w_in[512 + kA];
            float4 bb = *(const float4*)&b_in[kA];
            float W0[4] = {w0.x, w0.y, w0.z, w0.w};
            float W1[4] = {w1.x, w1.y, w1.z, w1.w};
            float W2[4] = {w2.x, w2.y, w2.z, w2.w};
            float BB[4] = {bb.x, bb.y, bb.z, bb.w};
            #pragma unroll
            for (int e = 0; e < 4; ++e) {
                float pre = x0 * W0[e] + x1 * W1[e] + x2 * W2[e] + BB[e];
                float sig = frcp(1.f + __expf(-pre));
                float sp  = sig * (1.f + pre * (1.f - sig));
                vA[e]      = pre * sig;
                vA[4 + e]  = sp * W0[e];
                vA[8 + e]  = sp * W1[e];
                vA[12 + e] = sp * W2[e];
            }
        }
        const int k3 = kq & 7;
        {
            float4 w0 = *(const float4*)&w_in[kA + 32];
            float4 w1 = *(const float4*)&w_in[256 + kA + 32];
            float4 w2 = *(const float4*)&w_in[512 + kA + 32];
            float4 bb = *(const float4*)&b_in[kA + 32];
            float W0[4] = {w0.x, w0.y, w0.z, w0.w};
            float W1[4] = {w1.x, w1.y, w1.z, w1.w};
            float W2[4] = {w2.x, w2.y, w2.z, w2.w};
            float BB[4] = {bb.x, bb.y, bb.z, bb.w};
            float sp[4], h0[4];
            #pragma unroll
            for (int e = 0; e < 4; ++e) {
                float pre = x0 * W0[e] + x1 * W1[e] + x2 * W2[e] + BB[e];
                float sig = frcp(1.f + __expf(-pre));
                sp[e] = sig * (1.f + pre * (1.f - sig));
                h0[e] = pre * sig;
            }
            {   // r = 0 row
                uint32_t hw[4];
                #pragma unroll
                for (int e = 0; e < 4; ++e) hw[e] = pkrtz(vA[e], h0[e]);
                *(uint4*)&lds[(kq << 7) + (((4 * s) ^ k3) << 2)] = *(uint4*)hw;
            }
            #pragma unroll
            for (int r = 1; r < 4; ++r) {          // derivative rows
                uint32_t hw[4];
                #pragma unroll
                for (int e = 0; e < 4; ++e) {
                    float wB = (r == 1) ? W0[e] : (r == 2) ? W1[e] : W2[e];
                    hw[e] = pkrtz(vA[4 * r + e], sp[e] * wB);
                }
                *(uint4*)&lds[(kq << 7) + (((4 * s + r) ^ k3) << 2)] = *(uint4*)hw;
            }
        }
    }
    BARRIER();                                     // LDS-only wait

    // A-frag LDS word bases: slot j = tt&3 (kq = 2*tt+l5 -> kq&7 period 4 in tt).
    int abase[4];
    #pragma unroll
    for (int j = 0; j < 4; ++j) {
        const int kq = 2 * j + l5;
        abase[j] = (kq << 7) + ((ln ^ (kq & 7)) << 2);
    }

    #pragma unroll 1
    for (int l = 0; l < 4; ++l) {
        const int rdoff = (l & 1) ? PP : 0;        // read plane
        const int wroff = (l & 1) ? 0 : PP;        // write plane (epilogue)
        f32x16 acc[2];
        acc[0] = (f32x16)0.0f;
        acc[1] = (f32x16)0.0f;

        #pragma unroll
        for (int tt = 0; tt < 16; ++tt) {          // fully unrolled K-loop
            const int slot = tt & 3;
            // A frag: zero per-step address VALU (base reg + immediate)
            const int aw = rdoff + abase[tt & 3] + (tt >> 2) * 1024;
            FragH a;
            *(uint4*)&a.u[0] = *(const uint4*)&lds[aw];

            // MFMA straight from the ring (WAR with refill below; no copies)
            acc[0] = mfma16(a.v, qh[slot][0], acc[0]);
            acc[1] = mfma16(a.v, qh[slot][1], acc[1]);

            // refill this slot with chunk lin+4 (uniform base -> saddr form).
            // SKIP the dead tail: l==3, tt>=12 would load never-consumed data.
            if (tt < 12 || l < 3) {
                int lin = l * 16 + tt + 4;
                if (lin > NCHUNK_TOT - 1) lin = NCHUNK_TOT - 1;
                const uint32_t* Bc = Wp + lin * CHUNK_WORDS;
                qh[slot][0] = *(const uint4*)(Bc + voff);
                qh[slot][1] = *(const uint4*)(Bc + voff + 128);
            }
        }

        if (l < 3) {
            // bias loads (global, no LDS dependence)
            const float bn0 = b_hid[l * 256 + n1];
            const float bn1 = b_hid[l * 256 + n1 + 32];
            // NO barrier here: epilogue writes the OTHER plane (wroff).
            // C layout per acc: col = n (lane ln), row = st + 8*rg + 4*l5
            // This lane writes pair p = cg*32+ln = cols (n1, n1+32) for 16 rows.
            const int kq    = cg * 8 + (ln >> 2);  // p>>2 ; kq&7 == ln>>2
            const int xr    = ln >> 2;
            const int wbase = wroff + (kq << 7) + (ln & 3);
            #pragma unroll
            for (int rg = 0; rg < 4; ++rg) {
                float v0[4], v1[4];
                {
                    const float pre = acc[0][rg * 4 + 0] + bn0;
                    const float sig = frcp(1.f + __expf(-pre));
                    const float sp  = sig * (1.f + pre * (1.f - sig));
                    v0[0] = pre * sig;
                    v0[1] = sp * acc[0][rg * 4 + 1];
                    v0[2] = sp * acc[0][rg * 4 + 2];
                    v0[3] = sp * acc[0][rg * 4 + 3];
                }
                {
                    const float pre = acc[1][rg * 4 + 0] + bn1;
                    const float sig = frcp(1.f + __expf(-pre));
                    const float sp  = sig * (1.f + pre * (1.f - sig));
                    v1[0] = pre * sig;
                    v1[1] = sp * acc[1][rg * 4 + 1];
                    v1[2] = sp * acc[1][rg * 4 + 2];
                    v1[3] = sp * acc[1][rg * 4 + 3];
                }
                const int mb = 8 * rg + 4 * l5;
                #pragma unroll
                for (int st = 0; st < 4; ++st) {
                    const int a = wbase + (((mb + st) ^ xr) << 2);
                    lds[a] = pkrtz(v0[st], v1[st]);
                }
            }
            BARRIER();                             // sA(l+1) visible to all
        } else {
            BARRIER();                             // all waves done READING plane 1
            // dump raw output-GEMM results to E[smp][state][n] fp32 (32 KB,
            // overlays both planes -- sA is dead here)
            float* E = (float*)lds;
            #pragma unroll
            for (int ct = 0; ct < 2; ++ct) {
                const int n = n1 + ct * 32;
                #pragma unroll
                for (int rg = 0; rg < 4; ++rg) {
                    const int smp = 2 * rg + l5;
                    #pragma unroll
                    for (int st = 0; st < 4; ++st)
                        E[(smp * 4 + st) * 256 + n] = acc[ct][rg * 4 + st];
                }
            }
            BARRIER();
            // final phase: lane = mixture, wave w -> samples 2w..2w+1.
            // No max-subtraction: |logits| << 88, f32 exp cannot overflow.
            const float4* E4 = (const float4*)lds;
            float4 bo = *(const float4*)&b_out[lane * 4];
            #pragma unroll
            for (int g = 0; g < 2; ++g) {
                const int sl = wave * 2 + g;       // 0..7
                float4 o  = E4[(sl * 4 + 0) * 64 + lane];
                float4 t1 = E4[(sl * 4 + 1) * 64 + lane];
                float4 t2 = E4[(sl * 4 + 2) * 64 + lane];
                float4 t3 = E4[(sl * 4 + 3) * 64 + lane];
                float sm  = o.x + bo.x;
                float oa0 = o.y + bo.y, oa1 = o.z + bo.z, oa2 = o.w + bo.w;
                float ds0 = t1.x, ds1 = t2.x, ds2 = t3.x;
                float e  = __expf(sm);
                float Z  = wsum(e);
                float rZ = frcp(Z);
                float T0 = wsum(e * ds0) * rZ;
                float T1 = wsum(e * ds1) * rZ;
                float T2 = wsum(e * ds2) * rZ;
                float g0 =  (ds1 - T1) * oa0 + t2.y + (ds2 - T2) * oa1 + t3.z;
                float g1 = -((ds0 - T0) * oa0 + t1.y) + (ds2 - T2) * oa2 + t3.w;
                float g2 = -((ds0 - T0) * oa1 + t1.z) - ((ds1 - T1) * oa2 + t2.w);
                float u0 = wsum(e * g0) * rZ;
                float u1 = wsum(e * g1) * rZ;
                float u2 = wsum(e * g2) * rZ;
                if (lane == 0) {
                    const int sg = s0 + sl;
                    out[sg * 3 + 0] = u0;
                    out[sg * 3 + 1] = u1;
                    out[sg * 3 + 2] = u2;
                }
            }
        }
    }
}

extern "C" void kernel_launch(void* const* d_in, const int* in_sizes, int n_in,
                              void* d_out, int out_size, void* d_ws, size_t ws_size,
                              hipStream_t stream) {
    const float* x     = (const float*)d_in[0];
    const float* w_in  = (const float*)d_in[1];
    const float* b_in  = (const float*)d_in[2];
    const float* w_hid = (const float*)d_in[3];
    const float* b_hid = (const float*)d_in[4];
    const float* w_out = (const float*)d_in[5];
    const float* b_out = (const float*)d_in[6];
    float* out = (float*)d_out;
    uint32_t* Wp = (uint32_t*)d_ws;                 // 512 KB packed-weight image
    const int N = in_sizes[0] / 3;

    pack_w<<<128, 256, 0, stream>>>(w_hid, w_out, Wp);
    divfree_mfma<<<N / SPB, THREADS, 0, stream>>>(x, Wp, w_in, b_in, b_hid, b_out, out);
}

// Round 19
// 261.871 us; speedup vs baseline: 1.0082x; 1.0082x over previous
//
#include <hip/hip_runtime.h>
#include <stdint.h>

#define THREADS 256
#define SPB 8                  // samples per block -> 32 A-rows
#define CHUNK_WORDS 2048       // one K=16 W chunk: dense f16-hi image (8 KB)
#define NCHUNK_TOT 64          // 4 layers x 16 chunks, linearized
#define PP 4096                // ping-pong plane stride in words (16 KB)

typedef _Float16 f16x8 __attribute__((ext_vector_type(8)));
typedef float f32x16 __attribute__((ext_vector_type(16)));

union FragH { uint32_t u[4]; f16x8 v; };

// Barrier that waits ONLY on LDS (lgkmcnt), not global loads: __syncthreads
// emits "s_waitcnt vmcnt(0) lgkmcnt(0); s_barrier", draining the in-flight
// B-ring prefetches at every layer boundary even though no cross-wave
// dependency flows through global memory here (all are LDS). Register
// consumers of qh[] are ordered by the compiler's per-register vmcnt
// tracking independently of barriers. Verified r17: 206.7->202.8 us.
#define BARRIER() asm volatile("s_waitcnt lgkmcnt(0)\n\ts_barrier" ::: "memory")

// ONE-OP packed f32x2 -> f16x2 (RTZ). Proven tolerable (absmax 3.66e-4).
__device__ __forceinline__ uint32_t pkrtz(float a, float b) {
    return __builtin_bit_cast(uint32_t, __builtin_amdgcn_cvt_pkrtz(a, b));
}
__device__ __forceinline__ float frcp(float x) {       // v_rcp_f32 (~1 ulp)
    return __builtin_amdgcn_rcpf(x);
}
__device__ __forceinline__ float wsum(float v) {
    #pragma unroll
    for (int off = 32; off > 0; off >>= 1) v += __shfl_xor(v, off, 64);
    return v;
}
// MFMA with B taken straight from the prefetch ring (no union round-trip)
__device__ __forceinline__ f32x16 mfma16(f16x8 a, uint4 b, f32x16 c) {
    return __builtin_amdgcn_mfma_f32_32x32x16_f16(a, __builtin_bit_cast(f16x8, b), c, 0, 0, 0);
}

// ---- pre-kernel: pack W into a DENSE f16-hi k-pair chunk image (512 KB) ----
// word idx = l*32768 + kt*2048 + s8*1024 + n*4 + w
// PAIR PERMUTATION: kp = kt*8+s8*4+w holds klo = 2*(kp&~31)+(kp&31), khi=klo+32
// -> a lane's two output columns (n, n+32) form one f16 k-pair IN-LANE.
__global__ __launch_bounds__(256) void pack_w(const float* __restrict__ w_hid,
                                              const float* __restrict__ w_out,
                                              uint32_t* __restrict__ Wp) {
    int t  = blockIdx.x * 256 + threadIdx.x;       // 0..32767
    int l  = t >> 13;
    int r  = t & 8191;
    int kt = r >> 9;
    int r2 = r & 511;
    int s8 = r2 >> 8;
    int n  = r2 & 255;
    const float* Wsrc = (l < 3) ? (w_hid + l * 65536) : w_out;
    uint32_t wd[4];
    #pragma unroll
    for (int w = 0; w < 4; ++w) {
        int kp  = kt * 8 + s8 * 4 + w;             // 0..127
        int klo = 2 * (kp & ~31) + (kp & 31);
        wd[w] = pkrtz(Wsrc[klo * 256 + n], Wsrc[(klo + 32) * 256 + n]);
    }
    *(uint4*)&Wp[l * 32768 + kt * 2048 + s8 * 1024 + n * 4] = *(uint4*)wd;
}

// FINAL STATE = round-17 kernel (best verified: 202.8 us dispatch / 262 us
// bench, no spill at (256,4)): sA 32 KB ping-pong (plane l&1 read, other
// written -> no pre-epilogue barrier), 4-deep qh[4][2] ring with
// uniform-base saddr, lgkmcnt-only barriers, register-lean two-half input
// layer, single-shot fp32 E overlay, s_setprio around MFMA.
//
// Session findings baked in:
//  - Register demand ~124 -> 4 waves/SIMD is this structure's ceiling
//    (r12-r16: every min_waves>=5 config spilled 0.26-9.5 GB).
//  - L2-BW not binding (r15: halving B traffic via SPB=16 SLOWED 206->230).
//  - r18 micro-trims (setprio removal, dead-tail skip) neutral-to-negative
//    -> reverted.
__global__ __launch_bounds__(THREADS, 4) void divfree_mfma(
    const float* __restrict__ x,
    const uint32_t* __restrict__ Wp,
    const float* __restrict__ w_in,
    const float* __restrict__ b_in,
    const float* __restrict__ b_hid,
    const float* __restrict__ b_out,
    float* __restrict__ out)
{
    __shared__ uint32_t lds[8192];                 // 32 KB = 2 ping-pong planes
    const int tid  = threadIdx.x;
    const int wave = tid >> 6, lane = tid & 63;
    const int l5 = lane >> 5, ln = lane & 31;
    const int s0 = blockIdx.x * SPB;
    const int cg = wave;                           // column group (64 cols)
    const int n1 = cg * 64 + ln;                   // lower output column
    const int voff = l5 * 1024 + n1 * 4;           // per-lane B word offset

    // 4-deep software-pipelined B prefetch (hi image), 2 col-tiles/slot.
    // These 8 loads stay in flight across the input layer AND its barrier.
    uint4 qh[4][2];
    #pragma unroll
    for (int c = 0; c < 4; ++c) {
        const uint32_t* Bc = Wp + c * CHUNK_WORDS; // uniform base -> saddr
        qh[c][0] = *(const uint4*)(Bc + voff);
        qh[c][1] = *(const uint4*)(Bc + voff + 128);
    }

    { // ---- input layer, register-lean two-half form ----
      // thread owns (kq = tid&31, sample s = tid>>5); covers 4 state rows.
      // A-half computed fully first; only vA[16] carries into the B-half.
        const int kq = tid & 31;                   // 0..31
        const int s  = tid >> 5;                   // 0..7
        const int kA = ((kq >> 3) << 6) + ((kq & 7) << 2);
        const float x0 = x[(s0 + s) * 3 + 0];
        const float x1 = x[(s0 + s) * 3 + 1];
        const float x2 = x[(s0 + s) * 3 + 2];
        float vA[16];                              // [r*4+e]
        {
            float4 w0 = *(const float4*)&w_in[kA];
            float4 w1 = *(const float4*)&w_in[256 + kA];
            float4 w2 = *(const float4*)&w_in[512 + kA];
            float4 bb = *(const float4*)&b_in[kA];
            float W0[4] = {w0.x, w0.y, w0.z, w0.w};
            float W1[4] = {w1.x, w1.y, w1.z, w1.w};
            float W2[4] = {w2.x, w2.y, w2.z, w2.w};
            float BB[4] = {bb.x, bb.y, bb.z, bb.w};
            #pragma unroll
            for (int e = 0; e < 4; ++e) {
                float pre = x0 * W0[e] + x1 * W1[e] + x2 * W2[e] + BB[e];
                float sig = frcp(1.f + __expf(-pre));
                float sp  = sig * (1.f + pre * (1.f - sig));
                vA[e]      = pre * sig;
                vA[4 + e]  = sp * W0[e];
                vA[8 + e]  = sp * W1[e];
                vA[12 + e] = sp * W2[e];
            }
        }
        const int k3 = kq & 7;
        {
            float4 w0 = *(const float4*)&w_in[kA + 32];
            float4 w1 = *(const float4*)&w_in[256 + kA + 32];
            float4 w2 = *(const float4*)&w_in[512 + kA + 32];
            float4 bb = *(const float4*)&b_in[kA + 32];
            float W0[4] = {w0.x, w0.y, w0.z, w0.w};
            float W1[4] = {w1.x, w1.y, w1.z, w1.w};
            float W2[4] = {w2.x, w2.y, w2.z, w2.w};
            float BB[4] = {bb.x, bb.y, bb.z, bb.w};
            float sp[4], h0[4];
            #pragma unroll
            for (int e = 0; e < 4; ++e) {
                float pre = x0 * W0[e] + x1 * W1[e] + x2 * W2[e] + BB[e];
                float sig = frcp(1.f + __expf(-pre));
                sp[e] = sig * (1.f + pre * (1.f - sig));
                h0[e] = pre * sig;
            }
            {   // r = 0 row
                uint32_t hw[4];
                #pragma unroll
                for (int e = 0; e < 4; ++e) hw[e] = pkrtz(vA[e], h0[e]);
                *(uint4*)&lds[(kq << 7) + (((4 * s) ^ k3) << 2)] = *(uint4*)hw;
            }
            #pragma unroll
            for (int r = 1; r < 4; ++r) {          // derivative rows
                uint32_t hw[4];
                #pragma unroll
                for (int e = 0; e < 4; ++e) {
                    float wB = (r == 1) ? W0[e] : (r == 2) ? W1[e] : W2[e];
                    hw[e] = pkrtz(vA[4 * r + e], sp[e] * wB);
                }
                *(uint4*)&lds[(kq << 7) + (((4 * s + r) ^ k3) << 2)] = *(uint4*)hw;
            }
        }
    }
    BARRIER();                                     // LDS-only wait

    // A-frag LDS word bases: slot j = tt&3 (kq = 2*tt+l5 -> kq&7 period 4 in tt).
    int abase[4];
    #pragma unroll
    for (int j = 0; j < 4; ++j) {
        const int kq = 2 * j + l5;
        abase[j] = (kq << 7) + ((ln ^ (kq & 7)) << 2);
    }

    #pragma unroll 1
    for (int l = 0; l < 4; ++l) {
        const int rdoff = (l & 1) ? PP : 0;        // read plane
        const int wroff = (l & 1) ? 0 : PP;        // write plane (epilogue)
        f32x16 acc[2];
        acc[0] = (f32x16)0.0f;
        acc[1] = (f32x16)0.0f;

        #pragma unroll
        for (int tt = 0; tt < 16; ++tt) {          // fully unrolled K-loop
            const int slot = tt & 3;
            // A frag: zero per-step address VALU (base reg + immediate)
            const int aw = rdoff + abase[tt & 3] + (tt >> 2) * 1024;
            FragH a;
            *(uint4*)&a.u[0] = *(const uint4*)&lds[aw];

            // MFMA FIRST, straight from the ring (WAR with refill below)
            __builtin_amdgcn_s_setprio(1);
            acc[0] = mfma16(a.v, qh[slot][0], acc[0]);
            acc[1] = mfma16(a.v, qh[slot][1], acc[1]);
            __builtin_amdgcn_s_setprio(0);

            // refill this slot with chunk lin+4 (uniform base -> saddr form)
            int lin = l * 16 + tt + 4;
            if (lin > NCHUNK_TOT - 1) lin = NCHUNK_TOT - 1;
            const uint32_t* Bc = Wp + lin * CHUNK_WORDS;
            qh[slot][0] = *(const uint4*)(Bc + voff);
            qh[slot][1] = *(const uint4*)(Bc + voff + 128);
        }

        if (l < 3) {
            // bias loads (global, no LDS dependence)
            const float bn0 = b_hid[l * 256 + n1];
            const float bn1 = b_hid[l * 256 + n1 + 32];
            // NO barrier here: epilogue writes the OTHER plane (wroff).
            // C layout per acc: col = n (lane ln), row = st + 8*rg + 4*l5
            // This lane writes pair p = cg*32+ln = cols (n1, n1+32) for 16 rows.
            const int kq    = cg * 8 + (ln >> 2);  // p>>2 ; kq&7 == ln>>2
            const int xr    = ln >> 2;
            const int wbase = wroff + (kq << 7) + (ln & 3);
            #pragma unroll
            for (int rg = 0; rg < 4; ++rg) {
                float v0[4], v1[4];
                {
                    const float pre = acc[0][rg * 4 + 0] + bn0;
                    const float sig = frcp(1.f + __expf(-pre));
                    const float sp  = sig * (1.f + pre * (1.f - sig));
                    v0[0] = pre * sig;
                    v0[1] = sp * acc[0][rg * 4 + 1];
                    v0[2] = sp * acc[0][rg * 4 + 2];
                    v0[3] = sp * acc[0][rg * 4 + 3];
                }
                {
                    const float pre = acc[1][rg * 4 + 0] + bn1;
                    const float sig = frcp(1.f + __expf(-pre));
                    const float sp  = sig * (1.f + pre * (1.f - sig));
                    v1[0] = pre * sig;
                    v1[1] = sp * acc[1][rg * 4 + 1];
                    v1[2] = sp * acc[1][rg * 4 + 2];
                    v1[3] = sp * acc[1][rg * 4 + 3];
                }
                const int mb = 8 * rg + 4 * l5;
                #pragma unroll
                for (int st = 0; st < 4; ++st) {
                    const int a = wbase + (((mb + st) ^ xr) << 2);
                    lds[a] = pkrtz(v0[st], v1[st]);
                }
            }
            BARRIER();                             // sA(l+1) visible to all
        } else {
            BARRIER();                             // all waves done READING plane 1
            // dump raw output-GEMM results to E[smp][state][n] fp32 (32 KB,
            // overlays both planes -- sA is dead here)
            float* E = (float*)lds;
            #pragma unroll
            for (int ct = 0; ct < 2; ++ct) {
                const int n = n1 + ct * 32;
                #pragma unroll
                for (int rg = 0; rg < 4; ++rg) {
                    const int smp = 2 * rg + l5;
                    #pragma unroll
                    for (int st = 0; st < 4; ++st)
                        E[(smp * 4 + st) * 256 + n] = acc[ct][rg * 4 + st];
                }
            }
            BARRIER();
            // final phase: lane = mixture, wave w -> samples 2w..2w+1.
            // No max-subtraction: |logits| << 88, f32 exp cannot overflow.
            const float4* E4 = (const float4*)lds;
            float4 bo = *(const float4*)&b_out[lane * 4];
            #pragma unroll
            for (int g = 0; g < 2; ++g) {
                const int sl = wave * 2 + g;       // 0..7
                float4 o  = E4[(sl * 4 + 0) * 64 + lane];
                float4 t1 = E4[(sl * 4 + 1) * 64 + lane];
                float4 t2 = E4[(sl * 4 + 2) * 64 + lane];
                float4 t3 = E4[(sl * 4 + 3) * 64 + lane];
                float sm  = o.x + bo.x;
                float oa0 = o.y + bo.y, oa1 = o.z + bo.z, oa2 = o.w + bo.w;
                float ds0 = t1.x, ds1 = t2.x, ds2 = t3.x;
                float e  = __expf(sm);
                float Z  = wsum(e);
                float rZ = frcp(Z);
                float T0 = wsum(e * ds0) * rZ;
                float T1 = wsum(e * ds1) * rZ;
                float T2 = wsum(e * ds2) * rZ;
                float g0 =  (ds1 - T1) * oa0 + t2.y + (ds2 - T2) * oa1 + t3.z;
                float g1 = -((ds0 - T0) * oa0 + t1.y) + (ds2 - T2) * oa2 + t3.w;
                float g2 = -((ds0 - T0) * oa1 + t1.z) - ((ds1 - T1) * oa2 + t2.w);
                float u0 = wsum(e * g0) * rZ;
                float u1 = wsum(e * g1) * rZ;
                float u2 = wsum(e * g2) * rZ;
                if (lane == 0) {
                    const int sg = s0 + sl;
                    out[sg * 3 + 0] = u0;
                    out[sg * 3 + 1] = u1;
                    out[sg * 3 + 2] = u2;
                }
            }
        }
    }
}

extern "C" void kernel_launch(void* const* d_in, const int* in_sizes, int n_in,
                              void* d_out, int out_size, void* d_ws, size_t ws_size,
                              hipStream_t stream) {
    const float* x     = (const float*)d_in[0];
    const float* w_in  = (const float*)d_in[1];
    const float* b_in  = (const float*)d_in[2];
    const float* w_hid = (const float*)d_in[3];
    const float* b_hid = (const float*)d_in[4];
    const float* w_out = (const float*)d_in[5];
    const float* b_out = (const float*)d_in[6];
    float* out = (float*)d_out;
    uint32_t* Wp = (uint32_t*)d_ws;                 // 512 KB packed-weight image
    const int N = in_sizes[0] / 3;

    pack_w<<<128, 256, 0, stream>>>(w_hid, w_out, Wp);
    divfree_mfma<<<N / SPB, THREADS, 0, stream>>>(x, Wp, w_in, b_in, b_hid, b_out, out);
}